// Round 5
// baseline (334.748 us; speedup 1.0000x reference)
//
#include <hip/hip_runtime.h>
#include <cmath>

// INGP hashgrid encode.
//   Gather model (validated R9): bound by random L2 line-lookups at ~4.4us/M.
//   Morton-bin sort (32^3) makes wave lanes spatially adjacent -> TA merges
//   coarse/mid-level corner lookups: gather 203 -> 146us (quantitative match).
//   Finer bins CANNOT help: wave extent is density-set (~1/20 per dim),
//   already below bin size. Fine levels 8-15 at random-lookup floor.
//   R10: cut the sort-pipeline overhead that ate R9's win:
//   - packed scatter: ONE aligned 16B store {x,y,z,bits(i)} per point
//     (1 scattered line-RMW/pt instead of 2.2 for 12B+4B two-region stores).
//   - hist/offs/pts4 live in d_out (all dead before transpose writes d_out;
//     gather never writes d_out -> no race). perm lives in ws tail -> ws ask
//     66MB, below R9's proven 66.25MB.
//   - gather reads points directly (vf4, coalesced 16 lines/wave) -- R6
//     proved LDS point-staging is neutral; drops a barrier + 6KB LDS.
//   Schedule: fine levels 8-15 XCD-pinned (table L2-resident); coarse 0-7
//   unpinned (post-sort footprints tiny). R5 lesson: no partial-line
//   cross-XCD output scatter -> level-major ws + LDS-tile transpose, perm
//   applied as full 128B-row scatter there.

constexpr int LVLS = 16;
constexpr unsigned TBL = 1u << 19;
constexpr unsigned TMASK = TBL - 1u;
constexpr unsigned P1 = 2654435761u;
constexpr unsigned P2 = 805459861u;
constexpr int PTS_PER_BLOCK = 512;   // 256 threads x 2 points
constexpr int NBINS = 32768;         // 32^3 Morton bins

typedef float vf2 __attribute__((ext_vector_type(2)));
typedef float vf4 __attribute__((ext_vector_type(4)));

struct ResArr { float r[LVLS]; };

__device__ __forceinline__ unsigned spread5(unsigned v) {
    v &= 31u;
    v = (v | (v << 8)) & 0x100Fu;
    v = (v | (v << 4)) & 0x10C3u;
    v = (v | (v << 2)) & 0x1249u;
    return v;
}

__device__ __forceinline__ unsigned bin_key(float px, float py, float pz) {
    float x = (px + 1.0f) * 0.5f;
    float y = (py + 1.0f) * 0.5f;
    float z = (pz + 1.0f) * 0.5f;
    unsigned bx = (unsigned)fminf(31.f, fmaxf(0.f, floorf(x * 32.f)));
    unsigned by = (unsigned)fminf(31.f, fmaxf(0.f, floorf(y * 32.f)));
    unsigned bz = (unsigned)fminf(31.f, fmaxf(0.f, floorf(z * 32.f)));
    return spread5(bx) | (spread5(by) << 1) | (spread5(bz) << 2);
}

__global__ __launch_bounds__(256) void ingp_hist(
    const float* __restrict__ pts, unsigned* __restrict__ hist, int npts)
{
    int i = blockIdx.x * 256 + threadIdx.x;
    if (i >= npts) return;
    float px = pts[i * 3 + 0], py = pts[i * 3 + 1], pz = pts[i * 3 + 2];
    atomicAdd(&hist[bin_key(px, py, pz)], 1u);
}

// Exclusive scan of 32768 bin counts, single block of 1024 threads.
__global__ __launch_bounds__(1024) void ingp_scan(
    const unsigned* __restrict__ hist, unsigned* __restrict__ offs)
{
    __shared__ unsigned sc[1024];
    int t = threadIdx.x;
    unsigned loc[32];
    unsigned s = 0;
    #pragma unroll
    for (int i = 0; i < 32; ++i) { loc[i] = s; s += hist[t * 32 + i]; }
    sc[t] = s;
    __syncthreads();
    for (int d = 1; d < 1024; d <<= 1) {
        unsigned v = (t >= d) ? sc[t - d] : 0u;
        __syncthreads();
        sc[t] += v;
        __syncthreads();
    }
    unsigned base = sc[t] - s;   // exclusive prefix of this thread's chunk
    #pragma unroll
    for (int i = 0; i < 32; ++i) offs[t * 32 + i] = base + loc[i];
}

// Packed scatter: one aligned 16B store per point {x,y,z,bits(orig idx)} +
// 4B perm (ws region, L2-absorbed).
__global__ __launch_bounds__(256) void ingp_scatter(
    const float* __restrict__ pts, unsigned* __restrict__ offs,
    vf4* __restrict__ pts4, int* __restrict__ perm, int npts)
{
    int i = blockIdx.x * 256 + threadIdx.x;
    if (i >= npts) return;
    float px = pts[i * 3 + 0], py = pts[i * 3 + 1], pz = pts[i * 3 + 2];
    unsigned pos = atomicAdd(&offs[bin_key(px, py, pz)], 1u);
    vf4 o; o.x = px; o.y = py; o.z = pz; o.w = __int_as_float(i);
    pts4[pos] = o;
    perm[pos] = i;
}

template<bool USE_WS, bool PACKED>
__global__ __launch_bounds__(256) void ingp_gather(
    const float* __restrict__ pts,    // PACKED=false: raw [N][3]
    const vf4* __restrict__ pts4,     // PACKED=true: sorted [N] {x,y,z,idx}
    const float* __restrict__ tables,
    float2* __restrict__ dst,     // USE_WS: [L][N] float2 ; else [N][L] float2
    ResArr ra, int npts, int bpl)
{
    __shared__ float s_res[LVLS];
    if (threadIdx.x < LVLS) s_res[threadIdx.x] = ra.r[threadIdx.x];
    __syncthreads();

    int b = blockIdx.x;
    int lvl, q;
    if (PACKED) {
        // phase 0: fine level 8+xcd, XCD-pinned. phase 1: coarse 0..7 unpinned.
        if (b < 8 * bpl) { lvl = 8 + (b & 7); q = b >> 3; }
        else { int u = b - 8 * bpl; lvl = u / bpl; q = u - lvl * bpl; }
    } else {
        // unsorted fallback: balanced pairing (k, 15-k), all pinned
        int phase_blocks = 8 * bpl;
        int xcd = b & 7;
        int phase = b / phase_blocks;
        lvl = phase == 0 ? xcd : 15 - xcd;
        q = (b % phase_blocks) >> 3;
    }
    int t = threadIdx.x;

    float r = s_res[lvl];
    const float2* __restrict__ tab = (const float2*)tables + (size_t)lvl * TBL;

    int p0 = q * PTS_PER_BLOCK + t;

    #pragma unroll
    for (int s = 0; s < 2; ++s) {
        int pglob = p0 + s * 256;      // global (sorted) point index
        bool valid = pglob < npts;
        int pp = valid ? pglob : 0;
        float px, py, pz;
        if (PACKED) {
            vf4 v = __builtin_nontemporal_load(pts4 + pp);
            px = v.x; py = v.y; pz = v.z;
        } else {
            px = __builtin_nontemporal_load(pts + pp * 3 + 0);
            py = __builtin_nontemporal_load(pts + pp * 3 + 1);
            pz = __builtin_nontemporal_load(pts + pp * 3 + 2);
        }
        float x = (px + 1.0f) * 0.5f;
        float y = (py + 1.0f) * 0.5f;
        float z = (pz + 1.0f) * 0.5f;
        float posx = x * r, posy = y * r, posz = z * r;
        float fx = floorf(posx), fy = floorf(posy), fz = floorf(posz);
        float wx = posx - fx, wy = posy - fy, wz = posz - fz;
        unsigned ix = (unsigned)fx, iy = (unsigned)fy, iz = (unsigned)fz;
        unsigned hx0 = ix,      hx1 = ix + 1u;
        unsigned hy0 = iy * P1;
        unsigned hz0 = iz * P2, hz1 = hz0 + P2;

        // yz-combination hashes (j,k): yz = j*2+k
        unsigned hyz[4];
        hyz[0] = hy0 ^ hz0;
        hyz[1] = hy0 ^ hz1;
        hyz[2] = (hy0 + P1) ^ hz0;
        hyz[3] = (hy0 + P1) ^ hz1;

        // v[i*4+yz]: corner (i,j,k)
        float2 v[8];
        if ((ix & 1u) == 0u) {
            // x-pair idx differ by ^1 -> one aligned float4 covers both.
            #pragma unroll
            for (int yz = 0; yz < 4; ++yz) {
                unsigned b0 = (hx0 ^ hyz[yz]) & TMASK;   // x=0 corner
                const vf4* lp4 = (const vf4*)(tab + (b0 & ~1u));
                vf4 qd = *lp4;
                float2 lo = make_float2(qd.x, qd.y);
                float2 hi = make_float2(qd.z, qd.w);
                bool odd = (b0 & 1u) != 0u;
                v[yz]     = odd ? hi : lo;   // x=0 corner
                v[4 + yz] = odd ? lo : hi;   // x=1 corner (idx = b0^1)
            }
        } else {
            #pragma unroll
            for (int yz = 0; yz < 4; ++yz) {
                unsigned b0 = (hx0 ^ hyz[yz]) & TMASK;
                unsigned b1 = (hx1 ^ hyz[yz]) & TMASK;
                v[yz]     = tab[b0];
                v[4 + yz] = tab[b1];
            }
        }

        float ox = 1.0f - wx, oy = 1.0f - wy, oz = 1.0f - wz;
        float w[8];
        w[0] = (ox * oy) * oz;   // (0,0,0)
        w[1] = (ox * oy) * wz;   // (0,0,1)
        w[2] = (ox * wy) * oz;   // (0,1,0)
        w[3] = (ox * wy) * wz;   // (0,1,1)
        w[4] = (wx * oy) * oz;   // (1,0,0)
        w[5] = (wx * oy) * wz;   // (1,0,1)
        w[6] = (wx * wy) * oz;   // (1,1,0)
        w[7] = (wx * wy) * wz;   // (1,1,1)

        float f0 = w[0] * v[0].x;
        float f1 = w[0] * v[0].y;
        #pragma unroll
        for (int c = 1; c < 8; ++c) {
            f0 += w[c] * v[c].x;
            f1 += w[c] * v[c].y;
        }
        if (valid) {
            vf2 o; o.x = f0; o.y = f1;
            if (USE_WS)
                __builtin_nontemporal_store(o, (vf2*)(dst + (size_t)lvl * npts + pglob));
            else
                dst[(size_t)pglob * LVLS + lvl] = make_float2(f0, f1);
        }
    }
}

// ws [L][N_sorted] float2 -> out [N_orig][L] float2 via perm (LDS tile).
// perm == nullptr -> identity (unsorted fallback).
__global__ __launch_bounds__(256) void ingp_transpose(
    const float2* __restrict__ ws, const int* __restrict__ perm,
    float4* __restrict__ out, int npts)
{
    __shared__ float2 a[LVLS][258];
    __shared__ int s_perm[256];
    int base = blockIdx.x * 256;
    int t = threadIdx.x;

    if (base + t < npts) s_perm[t] = perm ? perm[base + t] : base + t;

    #pragma unroll
    for (int l = 0; l < LVLS; ++l) {
        int pp = base + t;
        float2 val = make_float2(0.f, 0.f);
        if (pp < npts) {
            vf2 v = __builtin_nontemporal_load((const vf2*)(ws + (size_t)l * npts + pp));
            val = make_float2(v.x, v.y);
        }
        a[l][t] = val;
    }
    __syncthreads();

    int j = t & 7;
    int pl = t >> 3;
    #pragma unroll
    for (int it = 0; it < 8; ++it) {
        int pt = pl + it * 32;
        if (base + pt < npts) {
            int orig = s_perm[pt];
            float2 u = a[2 * j][pt];
            float2 v = a[2 * j + 1][pt];
            vf4 o; o.x = u.x; o.y = u.y; o.z = v.x; o.w = v.y;
            // row = 128B aligned; 8 lanes cover 2 full lines contiguously.
            __builtin_nontemporal_store(o, (vf4*)(out + (size_t)orig * 8 + j));
        }
    }
}

extern "C" void kernel_launch(void* const* d_in, const int* in_sizes, int n_in,
                              void* d_out, int out_size, void* d_ws, size_t ws_size,
                              hipStream_t stream) {
    const float* pts    = (const float*)d_in[0];
    const float* tables = (const float*)d_in[1];
    int npts = in_sizes[0] / 3;

    // numpy-bitwise RES: GROWTH = exp((log(2048)-log(16))/15); floor(16*G**l)
    ResArr ra;
    double growth = exp((log(2048.0) - log(16.0)) / 15.0);
    for (int l = 0; l < LVLS; ++l)
        ra.r[l] = (float)floor(16.0 * pow(growth, (double)l));

    int bpl = (npts + PTS_PER_BLOCK - 1) / PTS_PER_BLOCK;
    int grid = LVLS * bpl;
    int pgrid = (npts + 255) / 256;

    // ws layout:    [ws: L*N float2][perm: N int]
    // d_out scratch:[hist: NBINS u32][offs: NBINS u32][pts4: N vf4]
    //   (all d_out scratch is dead before transpose writes d_out; gather
    //    only READS d_out scratch and never writes d_out -> no race)
    size_t ws_needed = (size_t)LVLS * npts * sizeof(float2);
    size_t perm_bytes = (size_t)npts * sizeof(int);
    size_t out_scratch = 2ull * NBINS * sizeof(unsigned) + (size_t)npts * sizeof(vf4);
    bool use_ws = ws_size >= ws_needed;
    bool use_sort = use_ws && (ws_size >= ws_needed + perm_bytes)
                           && ((size_t)out_size >= out_scratch);

    if (use_sort) {
        float2*   ws   = (float2*)d_ws;
        int*      perm = (int*)((char*)d_ws + ws_needed);
        unsigned* hist = (unsigned*)d_out;
        unsigned* offs = hist + NBINS;
        vf4*      pts4 = (vf4*)((char*)d_out + 2ull * NBINS * sizeof(unsigned));

        hipMemsetAsync(hist, 0, NBINS * sizeof(unsigned), stream);
        hipLaunchKernelGGL(ingp_hist, dim3(pgrid), dim3(256), 0, stream,
                           pts, hist, npts);
        hipLaunchKernelGGL(ingp_scan, dim3(1), dim3(1024), 0, stream,
                           hist, offs);
        hipLaunchKernelGGL(ingp_scatter, dim3(pgrid), dim3(256), 0, stream,
                           pts, offs, pts4, perm, npts);
        hipLaunchKernelGGL((ingp_gather<true, true>), dim3(grid), dim3(256), 0, stream,
                           nullptr, pts4, tables, ws, ra, npts, bpl);
        hipLaunchKernelGGL(ingp_transpose, dim3(pgrid), dim3(256), 0, stream,
                           ws, perm, (float4*)d_out, npts);
    } else if (use_ws) {
        float2* ws = (float2*)d_ws;
        hipLaunchKernelGGL((ingp_gather<true, false>), dim3(grid), dim3(256), 0, stream,
                           pts, nullptr, tables, ws, ra, npts, bpl);
        hipLaunchKernelGGL(ingp_transpose, dim3(pgrid), dim3(256), 0, stream,
                           ws, (const int*)nullptr, (float4*)d_out, npts);
    } else {
        hipLaunchKernelGGL((ingp_gather<false, false>), dim3(grid), dim3(256), 0, stream,
                           pts, nullptr, tables, (float2*)d_out, ra, npts, bpl);
    }
}